// Round 17
// baseline (543.563 us; speedup 1.0000x reference)
//
#include <hip/hip_runtime.h>
#include <hip/hip_fp16.h>

#define NN 100000
#define NE 1600000
#define CH 64
#define STEPS 10
#define ALPHA 0.1f

#define BW 256                       // nodes per bucket
#define NB ((NN + BW - 1) / BW)      // 391 buckets
#define PBLK 256                     // partition blocks
#define PCHUNK (NE / PBLK)           // 6250 edges per partition block

typedef unsigned int uint;
typedef unsigned short ushort;
typedef unsigned long long ull;

// pack two f32 into bf16x2 word, RNE (low half = first arg)
__device__ inline uint pack_bf16x2(float x, float y) {
    uint ux = __float_as_uint(x);
    ux += 0x7FFFu + ((ux >> 16) & 1u);
    uint uy = __float_as_uint(y);
    uy += 0x7FFFu + ((uy >> 16) & 1u);
    return (ux >> 16) | (uy & 0xFFFF0000u);
}

// ---- phase 1: per-block LDS bucket histogram -> dense histAll write ----
__global__ __launch_bounds__(256) void
k_hist(const int* __restrict__ dst, int* __restrict__ histAll) {
    __shared__ int hist[NB];
    int tid = threadIdx.x;
    for (int i = tid; i < NB; i += 256) hist[i] = 0;
    __syncthreads();
    int s0 = blockIdx.x * PCHUNK;
    for (int i = s0 + tid; i < s0 + PCHUNK; i += 256)
        atomicAdd(&hist[dst[i] >> 8], 1);
    __syncthreads();
    for (int b = tid; b < NB; b += 256)
        histAll[blockIdx.x * NB + b] = hist[b];
}

// ---- phase 2a: per-bucket scan over blocks ----
__global__ __launch_bounds__(256) void
k_colscan(int* __restrict__ histAll, int* __restrict__ bcnt) {
    __shared__ int lds[256];
    int b = blockIdx.x, tid = threadIdx.x;
    int v = histAll[tid * NB + b];
    lds[tid] = v;
    __syncthreads();
    for (int off = 1; off < 256; off <<= 1) {
        int t = (tid >= off) ? lds[tid - off] : 0;
        __syncthreads();
        lds[tid] += t;
        __syncthreads();
    }
    histAll[tid * NB + b] = lds[tid] - v;
    if (tid == 255) bcnt[b] = lds[255];
}

// ---- phase 2b: exclusive scan of 391 bucket sums ----
__global__ void k_scanb(const int* __restrict__ bcnt, int* __restrict__ bbase) {
    __shared__ int lds[512];
    int tid = threadIdx.x;
    int v = (tid < NB) ? bcnt[tid] : 0;
    lds[tid] = v;
    __syncthreads();
    for (int off = 1; off < 512; off <<= 1) {
        int t = (tid >= off) ? lds[tid - off] : 0;
        __syncthreads();
        lds[tid] += t;
        __syncthreads();
    }
    if (tid < NB) bbase[tid] = lds[tid] - v;
    if (tid == 0) bbase[NB] = NE;
}

// ---- phase 3: scatter 4B (src | dl<<17) into reserved dense runs ----
__global__ __launch_bounds__(256) void
k_partA2(const int* __restrict__ src, const int* __restrict__ dst,
         const int* __restrict__ histAll, const int* __restrict__ bbase,
         uint* __restrict__ tmp) {
    __shared__ int gb[NB];
    __shared__ int lcur[NB];
    int tid = threadIdx.x;
    for (int b = tid; b < NB; b += 256) {
        gb[b] = bbase[b] + histAll[blockIdx.x * NB + b];
        lcur[b] = 0;
    }
    __syncthreads();
    int s0 = blockIdx.x * PCHUNK;
    for (int i = s0 + tid; i < s0 + PCHUNK; i += 256) {
        int d = dst[i];
        int b = d >> 8;
        int r = atomicAdd(&lcur[b], 1);
        tmp[gb[b] + r] = (uint)src[i] | ((uint)(d & 255) << 17);
    }
}

// ---- phase 4: per-bucket degree histogram -> dinv + rowptr ----
__global__ __launch_bounds__(256) void
k_partB1(const uint* __restrict__ tmp, const int* __restrict__ bbase,
         float* __restrict__ dinv, int* __restrict__ rowptr) {
    __shared__ int hist[256];
    __shared__ int lds[256];
    int b = blockIdx.x, tid = threadIdx.x;
    int nb0 = b * BW;
    int nodes = (NN - nb0 < BW) ? (NN - nb0) : BW;
    int base = bbase[b];
    int m = bbase[b + 1] - base;
    hist[tid] = 0;
    __syncthreads();
    for (int i = tid; i < m; i += 256)
        atomicAdd(&hist[(tmp[base + i] >> 17) & 255], 1);
    __syncthreads();
    int v = hist[tid];
    lds[tid] = v;
    __syncthreads();
    for (int off = 1; off < 256; off <<= 1) {
        int t = (tid >= off) ? lds[tid - off] : 0;
        __syncthreads();
        lds[tid] += t;
        __syncthreads();
    }
    if (tid < nodes) {
        dinv[nb0 + tid] = rsqrtf(fmaxf((float)v, 1.0f));
        rowptr[nb0 + tid] = base + lds[tid] - v;
    }
    if (b == 0 && tid == 0) rowptr[NN] = NE;
}

// ---- phase 5: per-bucket sort-by-dst -> 4B rec = src | (f16(w)>>1)<<17 ----
__global__ __launch_bounds__(256) void
k_partB2(const uint* __restrict__ tmp, const int* __restrict__ bbase,
         const float* __restrict__ dinv, uint* __restrict__ rec) {
    __shared__ int hist[256];
    __shared__ int lds[256];
    __shared__ int lcur[256];
    int b = blockIdx.x, tid = threadIdx.x;
    int nb0 = b * BW;
    int base = bbase[b];
    int m = bbase[b + 1] - base;
    hist[tid] = 0;
    __syncthreads();
    for (int i = tid; i < m; i += 256)
        atomicAdd(&hist[(tmp[base + i] >> 17) & 255], 1);
    __syncthreads();
    int v = hist[tid];
    lds[tid] = v;
    __syncthreads();
    for (int off = 1; off < 256; off <<= 1) {
        int t = (tid >= off) ? lds[tid - off] : 0;
        __syncthreads();
        lds[tid] += t;
        __syncthreads();
    }
    lcur[tid] = lds[tid] - v;     // exclusive offset within bucket
    __syncthreads();
    for (int i = tid; i < m; i += 256) {
        uint r = tmp[base + i];
        int dl = (r >> 17) & 255;
        int sv = (int)(r & 0x1FFFFu);
        float w = dinv[sv] * dinv[nb0 + dl];
        ushort hw = __half_as_ushort(__float2half_rn(w));
        int p = atomicAdd(&lcur[dl], 1);
        rec[base + p] = (uint)sv | ((uint)(hw >> 1) << 17);
    }
}

// ---- pack x (f32 [node][64]) -> xq (bf16 [node][64], 128B rows) ----
__global__ __launch_bounds__(256) void
k_xq(const float* __restrict__ x, uint2* __restrict__ xq) {
    int t = blockIdx.x * 256 + threadIdx.x;      // [0, NN*16)
    if (t >= NN * 16) return;
    float4 v = ((const float4*)x)[t];
    xq[t] = make_uint2(pack_bf16x2(v.x, v.y), pack_bf16x2(v.z, v.w));
}

// ---- propagation v3: one wave per node; q=lane>>3 owns edge slot (8 slots),
//      cl=lane&7 owns 8 channels (uint4). One gather instr = 8 rows x 1KB.
//      Batch 16 always (2 instr) + 8 predicated + rare tail. NT rec loads. ----
__global__ __launch_bounds__(256) void
k_prop(const int* __restrict__ rowptr, const uint* __restrict__ rec,
       const uint4* __restrict__ h, uint4* __restrict__ hn) {
    int wid  = (int)((blockIdx.x * (long long)blockDim.x + threadIdx.x) >> 6);
    int lane = threadIdx.x & 63;
    if (wid >= NN) return;
    int q  = lane >> 3;            // edge slot [0,8)
    int cl = lane & 7;             // uint4 slot (8 ch) [0,8)
    int start = rowptr[wid];
    int end   = rowptr[wid + 1];
    int safe  = start < NE ? start : NE - 1;

    float a0 = 0.f, a1 = 0.f, a2 = 0.f, a3 = 0.f;
    float a4 = 0.f, a5 = 0.f, a6 = 0.f, a7 = 0.f;

    #define GATHER_FMA(RV, ACTIVE)                                               \
        {                                                                        \
            int   s_ = (int)((RV) & 0x1FFFFu);                                   \
            float wt = (ACTIVE)                                                  \
                ? __half2float(__ushort_as_half((ushort)(((RV) >> 17) << 1)))    \
                : 0.0f;                                                          \
            uint4 hv = h[(long long)s_ * 8 + cl];                                \
            a0 = fmaf(__uint_as_float(hv.x << 16),         wt, a0);              \
            a1 = fmaf(__uint_as_float(hv.x & 0xFFFF0000u), wt, a1);              \
            a2 = fmaf(__uint_as_float(hv.y << 16),         wt, a2);              \
            a3 = fmaf(__uint_as_float(hv.y & 0xFFFF0000u), wt, a3);              \
            a4 = fmaf(__uint_as_float(hv.z << 16),         wt, a4);              \
            a5 = fmaf(__uint_as_float(hv.z & 0xFFFF0000u), wt, a5);              \
            a6 = fmaf(__uint_as_float(hv.w << 16),         wt, a6);              \
            a7 = fmaf(__uint_as_float(hv.w & 0xFFFF0000u), wt, a7);              \
        }

    // batch 1: 16 edges (2 gather instrs of 8 rows each) — always
    {
        uint rv[2];
        #pragma unroll
        for (int j = 0; j < 2; ++j) {
            int ix = start + 8 * j + q;
            rv[j] = __builtin_nontemporal_load(rec + (ix < end ? ix : safe));
        }
        #pragma unroll
        for (int j = 0; j < 2; ++j) {
            int ix = start + 8 * j + q;
            GATHER_FMA(rv[j], ix < end);
        }
    }
    // batch 2: 8 more edges if deg > 16 (covers <= 24, ~98%)
    if (end > start + 16) {
        int ix = start + 16 + q;
        uint rv = __builtin_nontemporal_load(rec + (ix < end ? ix : safe));
        GATHER_FMA(rv, ix < end);
    }
    // rare tail: deg > 24
    for (int p = start + 24; p < end; p += 8) {
        int ix = p + q;
        if (ix < end) {
            uint rv = __builtin_nontemporal_load(rec + ix);
            GATHER_FMA(rv, true);
        }
    }
    #undef GATHER_FMA

    // reduce across 8 edge slots (lane bits 3,4,5)
    a0 += __shfl_xor(a0, 8);  a1 += __shfl_xor(a1, 8);
    a2 += __shfl_xor(a2, 8);  a3 += __shfl_xor(a3, 8);
    a4 += __shfl_xor(a4, 8);  a5 += __shfl_xor(a5, 8);
    a6 += __shfl_xor(a6, 8);  a7 += __shfl_xor(a7, 8);
    a0 += __shfl_xor(a0, 16); a1 += __shfl_xor(a1, 16);
    a2 += __shfl_xor(a2, 16); a3 += __shfl_xor(a3, 16);
    a4 += __shfl_xor(a4, 16); a5 += __shfl_xor(a5, 16);
    a6 += __shfl_xor(a6, 16); a7 += __shfl_xor(a7, 16);
    a0 += __shfl_xor(a0, 32); a1 += __shfl_xor(a1, 32);
    a2 += __shfl_xor(a2, 32); a3 += __shfl_xor(a3, 32);
    a4 += __shfl_xor(a4, 32); a5 += __shfl_xor(a5, 32);
    a6 += __shfl_xor(a6, 32); a7 += __shfl_xor(a7, 32);

    if (q == 0) {
        ull* hd = (ull*)&hn[(long long)wid * 8 + cl];
        ull lo = (ull)pack_bf16x2(a0, a1) | ((ull)pack_bf16x2(a2, a3) << 32);
        ull hi = (ull)pack_bf16x2(a4, a5) | ((ull)pack_bf16x2(a6, a7) << 32);
        __builtin_nontemporal_store(lo, hd);
        __builtin_nontemporal_store(hi, hd + 1);
    }
}

// ---- deferred combine: out = alpha*x + (1-alpha)/STEPS * sum_t h_t ----
__global__ void k_sum10(const uint2* __restrict__ hbase, const float* __restrict__ x,
                        float* __restrict__ out, int total) {
    int i = blockIdx.x * blockDim.x + threadIdx.x;
    if (i >= total) return;
    float s0 = 0.f, s1 = 0.f, s2 = 0.f, s3 = 0.f;
    #pragma unroll
    for (int t = 0; t < STEPS; ++t) {
        uint2 v = hbase[(size_t)t * (NN * 16) + i];
        s0 += __uint_as_float(v.x << 16);
        s1 += __uint_as_float(v.x & 0xFFFF0000u);
        s2 += __uint_as_float(v.y << 16);
        s3 += __uint_as_float(v.y & 0xFFFF0000u);
    }
    float4 xv = ((const float4*)x)[i];
    float4 r;
    r.x = ALPHA * xv.x + (1.0f - ALPHA) * (s0 * (1.0f / STEPS));
    r.y = ALPHA * xv.y + (1.0f - ALPHA) * (s1 * (1.0f / STEPS));
    r.z = ALPHA * xv.z + (1.0f - ALPHA) * (s2 * (1.0f / STEPS));
    r.w = ALPHA * xv.w + (1.0f - ALPHA) * (s3 * (1.0f / STEPS));
    ((float4*)out)[i] = r;
}

extern "C" void kernel_launch(void* const* d_in, const int* in_sizes, int n_in,
                              void* d_out, int out_size, void* d_ws, size_t ws_size,
                              hipStream_t stream) {
    const float* x  = (const float*)d_in[0];
    const int*   ei = (const int*)d_in[1];     // [2, NE]: row0=src, row1=dst
    const int*   src = ei;
    const int*   dst = ei + NE;
    float* out = (float*)d_out;

    char* ws = (char*)d_ws;
    const size_t MB = 1024 * 1024;
    const size_t KB = 1024;
    int*   histAll = (int*)  (ws);                     // ~400 KB
    float* dinv    = (float*)(ws + 1 * MB);            // 400 KB
    int*   rowptr  = (int*)  (ws + 2 * MB);            // 400 KB (+1)
    int*   bcnt    = (int*)  (ws + 3 * MB);            // tiny
    int*   bbase   = (int*)  (ws + 3 * MB + 64 * KB);  // tiny (+1)
    uint*  rec     = (uint*) (ws + 5 * MB);            // 6.4 MB (final CSR, 4B recs)
    uint4* hbase   = (uint4*)(ws + 20 * MB);           // 10 x 12.8 MB = 128 MB
    uint*  tmp     = (uint*) (ws + 20 * MB);           // 6.4 MB (dead before prop 0)
    uint4* xq      = (uint4*)d_out;                    // 12.8 MB; dead by k_sum10

    const size_t HBUF = (size_t)NN * 8;                // uint4 per h buffer

    k_hist   <<<PBLK, 256, 0, stream>>>(dst, histAll);
    k_colscan<<<NB, 256, 0, stream>>>(histAll, bcnt);
    k_scanb  <<<1, 512, 0, stream>>>(bcnt, bbase);
    k_partA2 <<<PBLK, 256, 0, stream>>>(src, dst, histAll, bbase, tmp);
    k_partB1 <<<NB, 256, 0, stream>>>(tmp, bbase, dinv, rowptr);
    k_partB2 <<<NB, 256, 0, stream>>>(tmp, bbase, dinv, rec);
    k_xq     <<<(NN * 16 + 255) / 256, 256, 0, stream>>>(x, (uint2*)xq);

    const int propBlocks = (NN * 64 + 255) / 256;      // one wave per node

    const uint4* hcur = xq;
    for (int t = 0; t < STEPS; ++t) {
        uint4* hn = hbase + (size_t)t * HBUF;
        k_prop<<<propBlocks, 256, 0, stream>>>(rowptr, rec, hcur, hn);
        hcur = hn;
    }

    const int total = NN * 16;
    k_sum10<<<(total + 255) / 256, 256, 0, stream>>>((const uint2*)hbase, x, out, total);
}

// Round 18
// 510.662 us; speedup vs baseline: 1.0644x; 1.0644x over previous
//
#include <hip/hip_runtime.h>
#include <hip/hip_fp16.h>

#define NN 100000
#define NE 1600000
#define CH 64
#define STEPS 10
#define ALPHA 0.1f

#define BW 256                       // nodes per bucket
#define NB ((NN + BW - 1) / BW)      // 391 buckets
#define PBLK 256                     // partition blocks
#define PCHUNK (NE / PBLK)           // 6250 edges per partition block

typedef unsigned int uint;
typedef unsigned short ushort;
typedef unsigned long long ull;

// pack two f32 into bf16x2 word, RNE (low half = first arg)
__device__ inline uint pack_bf16x2(float x, float y) {
    uint ux = __float_as_uint(x);
    ux += 0x7FFFu + ((ux >> 16) & 1u);
    uint uy = __float_as_uint(y);
    uy += 0x7FFFu + ((uy >> 16) & 1u);
    return (ux >> 16) | (uy & 0xFFFF0000u);
}

// ---- phase 1: per-block LDS bucket histogram -> dense histAll write ----
__global__ __launch_bounds__(256) void
k_hist(const int* __restrict__ dst, int* __restrict__ histAll) {
    __shared__ int hist[NB];
    int tid = threadIdx.x;
    for (int i = tid; i < NB; i += 256) hist[i] = 0;
    __syncthreads();
    int s0 = blockIdx.x * PCHUNK;
    for (int i = s0 + tid; i < s0 + PCHUNK; i += 256)
        atomicAdd(&hist[dst[i] >> 8], 1);
    __syncthreads();
    for (int b = tid; b < NB; b += 256)
        histAll[blockIdx.x * NB + b] = hist[b];
}

// ---- phase 2a: per-bucket scan over blocks ----
__global__ __launch_bounds__(256) void
k_colscan(int* __restrict__ histAll, int* __restrict__ bcnt) {
    __shared__ int lds[256];
    int b = blockIdx.x, tid = threadIdx.x;
    int v = histAll[tid * NB + b];
    lds[tid] = v;
    __syncthreads();
    for (int off = 1; off < 256; off <<= 1) {
        int t = (tid >= off) ? lds[tid - off] : 0;
        __syncthreads();
        lds[tid] += t;
        __syncthreads();
    }
    histAll[tid * NB + b] = lds[tid] - v;
    if (tid == 255) bcnt[b] = lds[255];
}

// ---- phase 2b: exclusive scan of 391 bucket sums ----
__global__ void k_scanb(const int* __restrict__ bcnt, int* __restrict__ bbase) {
    __shared__ int lds[512];
    int tid = threadIdx.x;
    int v = (tid < NB) ? bcnt[tid] : 0;
    lds[tid] = v;
    __syncthreads();
    for (int off = 1; off < 512; off <<= 1) {
        int t = (tid >= off) ? lds[tid - off] : 0;
        __syncthreads();
        lds[tid] += t;
        __syncthreads();
    }
    if (tid < NB) bbase[tid] = lds[tid] - v;
    if (tid == 0) bbase[NB] = NE;
}

// ---- phase 3: scatter 4B (src | dl<<17) into reserved dense runs ----
__global__ __launch_bounds__(256) void
k_partA2(const int* __restrict__ src, const int* __restrict__ dst,
         const int* __restrict__ histAll, const int* __restrict__ bbase,
         uint* __restrict__ tmp) {
    __shared__ int gb[NB];
    __shared__ int lcur[NB];
    int tid = threadIdx.x;
    for (int b = tid; b < NB; b += 256) {
        gb[b] = bbase[b] + histAll[blockIdx.x * NB + b];
        lcur[b] = 0;
    }
    __syncthreads();
    int s0 = blockIdx.x * PCHUNK;
    for (int i = s0 + tid; i < s0 + PCHUNK; i += 256) {
        int d = dst[i];
        int b = d >> 8;
        int r = atomicAdd(&lcur[b], 1);
        tmp[gb[b] + r] = (uint)src[i] | ((uint)(d & 255) << 17);
    }
}

// ---- phase 4: per-bucket degree histogram -> dinv + rowptr ----
__global__ __launch_bounds__(256) void
k_partB1(const uint* __restrict__ tmp, const int* __restrict__ bbase,
         float* __restrict__ dinv, int* __restrict__ rowptr) {
    __shared__ int hist[256];
    __shared__ int lds[256];
    int b = blockIdx.x, tid = threadIdx.x;
    int nb0 = b * BW;
    int nodes = (NN - nb0 < BW) ? (NN - nb0) : BW;
    int base = bbase[b];
    int m = bbase[b + 1] - base;
    hist[tid] = 0;
    __syncthreads();
    for (int i = tid; i < m; i += 256)
        atomicAdd(&hist[(tmp[base + i] >> 17) & 255], 1);
    __syncthreads();
    int v = hist[tid];
    lds[tid] = v;
    __syncthreads();
    for (int off = 1; off < 256; off <<= 1) {
        int t = (tid >= off) ? lds[tid - off] : 0;
        __syncthreads();
        lds[tid] += t;
        __syncthreads();
    }
    if (tid < nodes) {
        dinv[nb0 + tid] = rsqrtf(fmaxf((float)v, 1.0f));
        rowptr[nb0 + tid] = base + lds[tid] - v;
    }
    if (b == 0 && tid == 0) rowptr[NN] = NE;
}

// ---- phase 5: per-bucket sort-by-dst -> 4B rec = src | (f16(w)>>1)<<17 ----
__global__ __launch_bounds__(256) void
k_partB2(const uint* __restrict__ tmp, const int* __restrict__ bbase,
         const float* __restrict__ dinv, uint* __restrict__ rec) {
    __shared__ int hist[256];
    __shared__ int lds[256];
    __shared__ int lcur[256];
    int b = blockIdx.x, tid = threadIdx.x;
    int nb0 = b * BW;
    int base = bbase[b];
    int m = bbase[b + 1] - base;
    hist[tid] = 0;
    __syncthreads();
    for (int i = tid; i < m; i += 256)
        atomicAdd(&hist[(tmp[base + i] >> 17) & 255], 1);
    __syncthreads();
    int v = hist[tid];
    lds[tid] = v;
    __syncthreads();
    for (int off = 1; off < 256; off <<= 1) {
        int t = (tid >= off) ? lds[tid - off] : 0;
        __syncthreads();
        lds[tid] += t;
        __syncthreads();
    }
    lcur[tid] = lds[tid] - v;     // exclusive offset within bucket
    __syncthreads();
    for (int i = tid; i < m; i += 256) {
        uint r = tmp[base + i];
        int dl = (r >> 17) & 255;
        int sv = (int)(r & 0x1FFFFu);
        float w = dinv[sv] * dinv[nb0 + dl];
        ushort hw = __half_as_ushort(__float2half_rn(w));
        int p = atomicAdd(&lcur[dl], 1);
        rec[base + p] = (uint)sv | ((uint)(hw >> 1) << 17);
    }
}

// ---- pack x (f32 [node][64]) -> xq (bf16 [node][64], 128B rows) ----
__global__ __launch_bounds__(256) void
k_xq(const float* __restrict__ x, uint2* __restrict__ xq) {
    int t = blockIdx.x * 256 + threadIdx.x;      // [0, NN*16)
    if (t >= NN * 16) return;
    float4 v = ((const float4*)x)[t];
    xq[t] = make_uint2(pack_bf16x2(v.x, v.y), pack_bf16x2(v.z, v.w));
}

// ---- propagation (round-16 layout + NT hints): one wave per node;
//      q=lane>>4 owns edge slot, cl=lane&15 owns 4 channels (uint2 bf16).
//      Batch 16 always + 8 predicated + rare loop. NT rec loads, NT hn store
//      keep the XCD L2 free for h rows (r17-proven FETCH halving). ----
__global__ __launch_bounds__(256) void
k_prop(const int* __restrict__ rowptr, const uint* __restrict__ rec,
       const uint2* __restrict__ h, uint2* __restrict__ hn) {
    int wid  = (int)((blockIdx.x * (long long)blockDim.x + threadIdx.x) >> 6);
    int lane = threadIdx.x & 63;
    if (wid >= NN) return;
    int q  = lane >> 4;
    int cl = lane & 15;
    int start = rowptr[wid];
    int end   = rowptr[wid + 1];
    int safe  = start < NE ? start : NE - 1;

    float a0 = 0.f, a1 = 0.f, a2 = 0.f, a3 = 0.f;

    #define GATHER_FMA(RV, ACTIVE)                                               \
        {                                                                        \
            int   s_ = (int)((RV) & 0x1FFFFu);                                   \
            float wt = (ACTIVE)                                                  \
                ? __half2float(__ushort_as_half((ushort)(((RV) >> 17) << 1)))    \
                : 0.0f;                                                          \
            uint2 hv = h[(long long)s_ * 16 + cl];                               \
            a0 = fmaf(__uint_as_float(hv.x << 16),        wt, a0);               \
            a1 = fmaf(__uint_as_float(hv.x & 0xFFFF0000u), wt, a1);              \
            a2 = fmaf(__uint_as_float(hv.y << 16),        wt, a2);               \
            a3 = fmaf(__uint_as_float(hv.y & 0xFFFF0000u), wt, a3);              \
        }

    {
        uint rv[4];
        #pragma unroll
        for (int j = 0; j < 4; ++j) {
            int ix = start + 4 * j + q;
            rv[j] = __builtin_nontemporal_load(rec + (ix < end ? ix : safe));
        }
        #pragma unroll
        for (int j = 0; j < 4; ++j) {
            int ix = start + 4 * j + q;
            GATHER_FMA(rv[j], ix < end);
        }
    }
    if (end > start + 16) {
        uint rv[2];
        #pragma unroll
        for (int j = 0; j < 2; ++j) {
            int ix = start + 16 + 4 * j + q;
            rv[j] = __builtin_nontemporal_load(rec + (ix < end ? ix : safe));
        }
        #pragma unroll
        for (int j = 0; j < 2; ++j) {
            int ix = start + 16 + 4 * j + q;
            GATHER_FMA(rv[j], ix < end);
        }
    }
    for (int p = start + 24; p < end; p += 4) {
        int ix = p + q;
        if (ix < end) {
            uint rv = __builtin_nontemporal_load(rec + ix);
            GATHER_FMA(rv, true);
        }
    }
    #undef GATHER_FMA

    a0 += __shfl_xor(a0, 16); a1 += __shfl_xor(a1, 16);
    a2 += __shfl_xor(a2, 16); a3 += __shfl_xor(a3, 16);
    a0 += __shfl_xor(a0, 32); a1 += __shfl_xor(a1, 32);
    a2 += __shfl_xor(a2, 32); a3 += __shfl_xor(a3, 32);

    if (q == 0) {
        long long o = (long long)wid * 16 + cl;
        ull pack = (ull)pack_bf16x2(a0, a1) | ((ull)pack_bf16x2(a2, a3) << 32);
        __builtin_nontemporal_store(pack, (ull*)&hn[o]);
    }
}

// ---- deferred combine: out = alpha*x + (1-alpha)/STEPS * sum_t h_t ----
__global__ void k_sum10(const uint2* __restrict__ hbase, const float* __restrict__ x,
                        float* __restrict__ out, int total) {
    int i = blockIdx.x * blockDim.x + threadIdx.x;
    if (i >= total) return;
    float s0 = 0.f, s1 = 0.f, s2 = 0.f, s3 = 0.f;
    #pragma unroll
    for (int t = 0; t < STEPS; ++t) {
        uint2 v = hbase[(size_t)t * (NN * 16) + i];
        s0 += __uint_as_float(v.x << 16);
        s1 += __uint_as_float(v.x & 0xFFFF0000u);
        s2 += __uint_as_float(v.y << 16);
        s3 += __uint_as_float(v.y & 0xFFFF0000u);
    }
    float4 xv = ((const float4*)x)[i];
    float4 r;
    r.x = ALPHA * xv.x + (1.0f - ALPHA) * (s0 * (1.0f / STEPS));
    r.y = ALPHA * xv.y + (1.0f - ALPHA) * (s1 * (1.0f / STEPS));
    r.z = ALPHA * xv.z + (1.0f - ALPHA) * (s2 * (1.0f / STEPS));
    r.w = ALPHA * xv.w + (1.0f - ALPHA) * (s3 * (1.0f / STEPS));
    ((float4*)out)[i] = r;
}

extern "C" void kernel_launch(void* const* d_in, const int* in_sizes, int n_in,
                              void* d_out, int out_size, void* d_ws, size_t ws_size,
                              hipStream_t stream) {
    const float* x  = (const float*)d_in[0];
    const int*   ei = (const int*)d_in[1];     // [2, NE]: row0=src, row1=dst
    const int*   src = ei;
    const int*   dst = ei + NE;
    float* out = (float*)d_out;

    char* ws = (char*)d_ws;
    const size_t MB = 1024 * 1024;
    const size_t KB = 1024;
    int*   histAll = (int*)  (ws);                     // ~400 KB
    float* dinv    = (float*)(ws + 1 * MB);            // 400 KB
    int*   rowptr  = (int*)  (ws + 2 * MB);            // 400 KB (+1)
    int*   bcnt    = (int*)  (ws + 3 * MB);            // tiny
    int*   bbase   = (int*)  (ws + 3 * MB + 64 * KB);  // tiny (+1)
    uint*  rec     = (uint*) (ws + 5 * MB);            // 6.4 MB (final CSR, 4B recs)
    uint2* hbase   = (uint2*)(ws + 20 * MB);           // 10 x 12.8 MB = 128 MB
    uint*  tmp     = (uint*) (ws + 20 * MB);           // 6.4 MB (dead before prop 0)
    uint2* xq      = (uint2*)d_out;                    // 12.8 MB; dead by k_sum10

    const size_t HBUF = (size_t)NN * 16;               // uint2 per h buffer

    k_hist   <<<PBLK, 256, 0, stream>>>(dst, histAll);
    k_colscan<<<NB, 256, 0, stream>>>(histAll, bcnt);
    k_scanb  <<<1, 512, 0, stream>>>(bcnt, bbase);
    k_partA2 <<<PBLK, 256, 0, stream>>>(src, dst, histAll, bbase, tmp);
    k_partB1 <<<NB, 256, 0, stream>>>(tmp, bbase, dinv, rowptr);
    k_partB2 <<<NB, 256, 0, stream>>>(tmp, bbase, dinv, rec);
    k_xq     <<<(NN * 16 + 255) / 256, 256, 0, stream>>>(x, xq);

    const int propBlocks = (NN * 64 + 255) / 256;      // one wave per node

    const uint2* hcur = xq;
    for (int t = 0; t < STEPS; ++t) {
        uint2* hn = hbase + (size_t)t * HBUF;
        k_prop<<<propBlocks, 256, 0, stream>>>(rowptr, rec, hcur, hn);
        hcur = hn;
    }

    const int total = NN * 16;
    k_sum10<<<(total + 255) / 256, 256, 0, stream>>>(hbase, x, out, total);
}

// Round 19
// 461.007 us; speedup vs baseline: 1.1791x; 1.1077x over previous
//
#include <hip/hip_runtime.h>
#include <hip/hip_fp16.h>

#define NN 100000
#define NE 1600000
#define CH 64
#define STEPS 10
#define ALPHA 0.1f

#define BW 256                       // nodes per bucket
#define NB ((NN + BW - 1) / BW)      // 391 buckets
#define PBLK 256                     // partition blocks
#define PCHUNK (NE / PBLK)           // 6250 edges per partition block

typedef unsigned int uint;
typedef unsigned short ushort;
typedef unsigned long long ull;

// pack two f32 into bf16x2 word, RNE (low half = first arg)
__device__ inline uint pack_bf16x2(float x, float y) {
    uint ux = __float_as_uint(x);
    ux += 0x7FFFu + ((ux >> 16) & 1u);
    uint uy = __float_as_uint(y);
    uy += 0x7FFFu + ((uy >> 16) & 1u);
    return (ux >> 16) | (uy & 0xFFFF0000u);
}

// ---- phase 1: per-block LDS bucket histogram -> dense histAll write ----
__global__ __launch_bounds__(256) void
k_hist(const int* __restrict__ dst, int* __restrict__ histAll) {
    __shared__ int hist[NB];
    int tid = threadIdx.x;
    for (int i = tid; i < NB; i += 256) hist[i] = 0;
    __syncthreads();
    int s0 = blockIdx.x * PCHUNK;
    for (int i = s0 + tid; i < s0 + PCHUNK; i += 256)
        atomicAdd(&hist[dst[i] >> 8], 1);
    __syncthreads();
    for (int b = tid; b < NB; b += 256)
        histAll[blockIdx.x * NB + b] = hist[b];
}

// ---- phase 2a: per-bucket scan over blocks ----
__global__ __launch_bounds__(256) void
k_colscan(int* __restrict__ histAll, int* __restrict__ bcnt) {
    __shared__ int lds[256];
    int b = blockIdx.x, tid = threadIdx.x;
    int v = histAll[tid * NB + b];
    lds[tid] = v;
    __syncthreads();
    for (int off = 1; off < 256; off <<= 1) {
        int t = (tid >= off) ? lds[tid - off] : 0;
        __syncthreads();
        lds[tid] += t;
        __syncthreads();
    }
    histAll[tid * NB + b] = lds[tid] - v;
    if (tid == 255) bcnt[b] = lds[255];
}

// ---- phase 2b: exclusive scan of 391 bucket sums ----
__global__ void k_scanb(const int* __restrict__ bcnt, int* __restrict__ bbase) {
    __shared__ int lds[512];
    int tid = threadIdx.x;
    int v = (tid < NB) ? bcnt[tid] : 0;
    lds[tid] = v;
    __syncthreads();
    for (int off = 1; off < 512; off <<= 1) {
        int t = (tid >= off) ? lds[tid - off] : 0;
        __syncthreads();
        lds[tid] += t;
        __syncthreads();
    }
    if (tid < NB) bbase[tid] = lds[tid] - v;
    if (tid == 0) bbase[NB] = NE;
}

// ---- phase 3: scatter 4B (src | dl<<17) into reserved dense runs ----
__global__ __launch_bounds__(256) void
k_partA2(const int* __restrict__ src, const int* __restrict__ dst,
         const int* __restrict__ histAll, const int* __restrict__ bbase,
         uint* __restrict__ tmp) {
    __shared__ int gb[NB];
    __shared__ int lcur[NB];
    int tid = threadIdx.x;
    for (int b = tid; b < NB; b += 256) {
        gb[b] = bbase[b] + histAll[blockIdx.x * NB + b];
        lcur[b] = 0;
    }
    __syncthreads();
    int s0 = blockIdx.x * PCHUNK;
    for (int i = s0 + tid; i < s0 + PCHUNK; i += 256) {
        int d = dst[i];
        int b = d >> 8;
        int r = atomicAdd(&lcur[b], 1);
        tmp[gb[b] + r] = (uint)src[i] | ((uint)(d & 255) << 17);
    }
}

// ---- phase 4: per-bucket degree histogram -> dinv + rowptr ----
__global__ __launch_bounds__(256) void
k_partB1(const uint* __restrict__ tmp, const int* __restrict__ bbase,
         float* __restrict__ dinv, int* __restrict__ rowptr) {
    __shared__ int hist[256];
    __shared__ int lds[256];
    int b = blockIdx.x, tid = threadIdx.x;
    int nb0 = b * BW;
    int nodes = (NN - nb0 < BW) ? (NN - nb0) : BW;
    int base = bbase[b];
    int m = bbase[b + 1] - base;
    hist[tid] = 0;
    __syncthreads();
    for (int i = tid; i < m; i += 256)
        atomicAdd(&hist[(tmp[base + i] >> 17) & 255], 1);
    __syncthreads();
    int v = hist[tid];
    lds[tid] = v;
    __syncthreads();
    for (int off = 1; off < 256; off <<= 1) {
        int t = (tid >= off) ? lds[tid - off] : 0;
        __syncthreads();
        lds[tid] += t;
        __syncthreads();
    }
    if (tid < nodes) {
        dinv[nb0 + tid] = rsqrtf(fmaxf((float)v, 1.0f));
        rowptr[nb0 + tid] = base + lds[tid] - v;
    }
    if (b == 0 && tid == 0) rowptr[NN] = NE;
}

// ---- phase 5: per-bucket sort-by-dst -> 4B rec = src | (f16(w)>>1)<<17 ----
__global__ __launch_bounds__(256) void
k_partB2(const uint* __restrict__ tmp, const int* __restrict__ bbase,
         const float* __restrict__ dinv, uint* __restrict__ rec) {
    __shared__ int hist[256];
    __shared__ int lds[256];
    __shared__ int lcur[256];
    int b = blockIdx.x, tid = threadIdx.x;
    int nb0 = b * BW;
    int base = bbase[b];
    int m = bbase[b + 1] - base;
    hist[tid] = 0;
    __syncthreads();
    for (int i = tid; i < m; i += 256)
        atomicAdd(&hist[(tmp[base + i] >> 17) & 255], 1);
    __syncthreads();
    int v = hist[tid];
    lds[tid] = v;
    __syncthreads();
    for (int off = 1; off < 256; off <<= 1) {
        int t = (tid >= off) ? lds[tid - off] : 0;
        __syncthreads();
        lds[tid] += t;
        __syncthreads();
    }
    lcur[tid] = lds[tid] - v;     // exclusive offset within bucket
    __syncthreads();
    for (int i = tid; i < m; i += 256) {
        uint r = tmp[base + i];
        int dl = (r >> 17) & 255;
        int sv = (int)(r & 0x1FFFFu);
        float w = dinv[sv] * dinv[nb0 + dl];
        ushort hw = __half_as_ushort(__float2half_rn(w));
        int p = atomicAdd(&lcur[dl], 1);
        rec[base + p] = (uint)sv | ((uint)(hw >> 1) << 17);
    }
}

// ---- pack x (f32 [node][64]) -> xq (bf16 [node][64], 128B rows) ----
__global__ __launch_bounds__(256) void
k_xq(const float* __restrict__ x, uint2* __restrict__ xq) {
    int t = blockIdx.x * 256 + threadIdx.x;      // [0, NN*16)
    if (t >= NN * 16) return;
    float4 v = ((const float4*)x)[t];
    xq[t] = make_uint2(pack_bf16x2(v.x, v.y), pack_bf16x2(v.z, v.w));
}

// ---- propagation (round-16 layout; plain rec loads, NT hn store only):
//      one wave per node; q=lane>>4 owns edge slot, cl=lane&15 owns 4 ch.
//      Batch 16 always + 8 predicated + rare loop. ----
__global__ __launch_bounds__(256) void
k_prop(const int* __restrict__ rowptr, const uint* __restrict__ rec,
       const uint2* __restrict__ h, uint2* __restrict__ hn) {
    int wid  = (int)((blockIdx.x * (long long)blockDim.x + threadIdx.x) >> 6);
    int lane = threadIdx.x & 63;
    if (wid >= NN) return;
    int q  = lane >> 4;
    int cl = lane & 15;
    int start = rowptr[wid];
    int end   = rowptr[wid + 1];
    int safe  = start < NE ? start : NE - 1;

    float a0 = 0.f, a1 = 0.f, a2 = 0.f, a3 = 0.f;

    #define GATHER_FMA(RV, ACTIVE)                                               \
        {                                                                        \
            int   s_ = (int)((RV) & 0x1FFFFu);                                   \
            float wt = (ACTIVE)                                                  \
                ? __half2float(__ushort_as_half((ushort)(((RV) >> 17) << 1)))    \
                : 0.0f;                                                          \
            uint2 hv = h[(long long)s_ * 16 + cl];                               \
            a0 = fmaf(__uint_as_float(hv.x << 16),        wt, a0);               \
            a1 = fmaf(__uint_as_float(hv.x & 0xFFFF0000u), wt, a1);              \
            a2 = fmaf(__uint_as_float(hv.y << 16),        wt, a2);               \
            a3 = fmaf(__uint_as_float(hv.y & 0xFFFF0000u), wt, a3);              \
        }

    {
        uint rv[4];
        #pragma unroll
        for (int j = 0; j < 4; ++j) {
            int ix = start + 4 * j + q;
            rv[j] = rec[ix < end ? ix : safe];
        }
        #pragma unroll
        for (int j = 0; j < 4; ++j) {
            int ix = start + 4 * j + q;
            GATHER_FMA(rv[j], ix < end);
        }
    }
    if (end > start + 16) {
        uint rv[2];
        #pragma unroll
        for (int j = 0; j < 2; ++j) {
            int ix = start + 16 + 4 * j + q;
            rv[j] = rec[ix < end ? ix : safe];
        }
        #pragma unroll
        for (int j = 0; j < 2; ++j) {
            int ix = start + 16 + 4 * j + q;
            GATHER_FMA(rv[j], ix < end);
        }
    }
    for (int p = start + 24; p < end; p += 4) {
        int ix = p + q;
        if (ix < end) {
            uint rv = rec[ix];
            GATHER_FMA(rv, true);
        }
    }
    #undef GATHER_FMA

    a0 += __shfl_xor(a0, 16); a1 += __shfl_xor(a1, 16);
    a2 += __shfl_xor(a2, 16); a3 += __shfl_xor(a3, 16);
    a0 += __shfl_xor(a0, 32); a1 += __shfl_xor(a1, 32);
    a2 += __shfl_xor(a2, 32); a3 += __shfl_xor(a3, 32);

    if (q == 0) {
        long long o = (long long)wid * 16 + cl;
        ull pack = (ull)pack_bf16x2(a0, a1) | ((ull)pack_bf16x2(a2, a3) << 32);
        __builtin_nontemporal_store(pack, (ull*)&hn[o]);
    }
}

// ---- deferred combine: out = alpha*x + (1-alpha)/STEPS * sum_t h_t ----
__global__ void k_sum10(const uint2* __restrict__ hbase, const float* __restrict__ x,
                        float* __restrict__ out, int total) {
    int i = blockIdx.x * blockDim.x + threadIdx.x;
    if (i >= total) return;
    float s0 = 0.f, s1 = 0.f, s2 = 0.f, s3 = 0.f;
    #pragma unroll
    for (int t = 0; t < STEPS; ++t) {
        uint2 v = hbase[(size_t)t * (NN * 16) + i];
        s0 += __uint_as_float(v.x << 16);
        s1 += __uint_as_float(v.x & 0xFFFF0000u);
        s2 += __uint_as_float(v.y << 16);
        s3 += __uint_as_float(v.y & 0xFFFF0000u);
    }
    float4 xv = ((const float4*)x)[i];
    float4 r;
    r.x = ALPHA * xv.x + (1.0f - ALPHA) * (s0 * (1.0f / STEPS));
    r.y = ALPHA * xv.y + (1.0f - ALPHA) * (s1 * (1.0f / STEPS));
    r.z = ALPHA * xv.z + (1.0f - ALPHA) * (s2 * (1.0f / STEPS));
    r.w = ALPHA * xv.w + (1.0f - ALPHA) * (s3 * (1.0f / STEPS));
    ((float4*)out)[i] = r;
}

extern "C" void kernel_launch(void* const* d_in, const int* in_sizes, int n_in,
                              void* d_out, int out_size, void* d_ws, size_t ws_size,
                              hipStream_t stream) {
    const float* x  = (const float*)d_in[0];
    const int*   ei = (const int*)d_in[1];     // [2, NE]: row0=src, row1=dst
    const int*   src = ei;
    const int*   dst = ei + NE;
    float* out = (float*)d_out;

    char* ws = (char*)d_ws;
    const size_t MB = 1024 * 1024;
    const size_t KB = 1024;
    int*   histAll = (int*)  (ws);                     // ~400 KB
    float* dinv    = (float*)(ws + 1 * MB);            // 400 KB
    int*   rowptr  = (int*)  (ws + 2 * MB);            // 400 KB (+1)
    int*   bcnt    = (int*)  (ws + 3 * MB);            // tiny
    int*   bbase   = (int*)  (ws + 3 * MB + 64 * KB);  // tiny (+1)
    uint*  rec     = (uint*) (ws + 5 * MB);            // 6.4 MB (final CSR, 4B recs)
    uint2* hbase   = (uint2*)(ws + 20 * MB);           // 10 x 12.8 MB = 128 MB
    uint*  tmp     = (uint*) (ws + 20 * MB);           // 6.4 MB (dead before prop 0)
    uint2* xq      = (uint2*)d_out;                    // 12.8 MB; dead by k_sum10

    const size_t HBUF = (size_t)NN * 16;               // uint2 per h buffer

    k_hist   <<<PBLK, 256, 0, stream>>>(dst, histAll);
    k_colscan<<<NB, 256, 0, stream>>>(histAll, bcnt);
    k_scanb  <<<1, 512, 0, stream>>>(bcnt, bbase);
    k_partA2 <<<PBLK, 256, 0, stream>>>(src, dst, histAll, bbase, tmp);
    k_partB1 <<<NB, 256, 0, stream>>>(tmp, bbase, dinv, rowptr);
    k_partB2 <<<NB, 256, 0, stream>>>(tmp, bbase, dinv, rec);
    k_xq     <<<(NN * 16 + 255) / 256, 256, 0, stream>>>(x, xq);

    const int propBlocks = (NN * 64 + 255) / 256;      // one wave per node

    const uint2* hcur = xq;
    for (int t = 0; t < STEPS; ++t) {
        uint2* hn = hbase + (size_t)t * HBUF;
        k_prop<<<propBlocks, 256, 0, stream>>>(rowptr, rec, hcur, hn);
        hcur = hn;
    }

    const int total = NN * 16;
    k_sum10<<<(total + 255) / 256, 256, 0, stream>>>(hbase, x, out, total);
}

// Round 20
// 442.737 us; speedup vs baseline: 1.2277x; 1.0413x over previous
//
#include <hip/hip_runtime.h>
#include <hip/hip_fp16.h>

#define NN 100000
#define NE 1600000
#define CH 64
#define STEPS 10
#define ALPHA 0.1f

#define BW 256                       // nodes per bucket
#define NB ((NN + BW - 1) / BW)      // 391 buckets
#define PBLK 256                     // partition blocks
#define PCHUNK (NE / PBLK)           // 6250 edges per partition block

typedef unsigned int uint;
typedef unsigned short ushort;
typedef unsigned long long ull;

// pack two f32 into bf16x2 word, RNE (low half = first arg)
__device__ inline uint pack_bf16x2(float x, float y) {
    uint ux = __float_as_uint(x);
    ux += 0x7FFFu + ((ux >> 16) & 1u);
    uint uy = __float_as_uint(y);
    uy += 0x7FFFu + ((uy >> 16) & 1u);
    return (ux >> 16) | (uy & 0xFFFF0000u);
}

// ---- phase 1: per-block LDS bucket histogram -> dense histAll write ----
__global__ __launch_bounds__(256) void
k_hist(const int* __restrict__ dst, int* __restrict__ histAll) {
    __shared__ int hist[NB];
    int tid = threadIdx.x;
    for (int i = tid; i < NB; i += 256) hist[i] = 0;
    __syncthreads();
    int s0 = blockIdx.x * PCHUNK;
    for (int i = s0 + tid; i < s0 + PCHUNK; i += 256)
        atomicAdd(&hist[dst[i] >> 8], 1);
    __syncthreads();
    for (int b = tid; b < NB; b += 256)
        histAll[blockIdx.x * NB + b] = hist[b];
}

// ---- phase 2a: per-bucket scan over blocks ----
__global__ __launch_bounds__(256) void
k_colscan(int* __restrict__ histAll, int* __restrict__ bcnt) {
    __shared__ int lds[256];
    int b = blockIdx.x, tid = threadIdx.x;
    int v = histAll[tid * NB + b];
    lds[tid] = v;
    __syncthreads();
    for (int off = 1; off < 256; off <<= 1) {
        int t = (tid >= off) ? lds[tid - off] : 0;
        __syncthreads();
        lds[tid] += t;
        __syncthreads();
    }
    histAll[tid * NB + b] = lds[tid] - v;
    if (tid == 255) bcnt[b] = lds[255];
}

// ---- phase 2b: exclusive scan of 391 bucket sums ----
__global__ void k_scanb(const int* __restrict__ bcnt, int* __restrict__ bbase) {
    __shared__ int lds[512];
    int tid = threadIdx.x;
    int v = (tid < NB) ? bcnt[tid] : 0;
    lds[tid] = v;
    __syncthreads();
    for (int off = 1; off < 512; off <<= 1) {
        int t = (tid >= off) ? lds[tid - off] : 0;
        __syncthreads();
        lds[tid] += t;
        __syncthreads();
    }
    if (tid < NB) bbase[tid] = lds[tid] - v;
    if (tid == 0) bbase[NB] = NE;
}

// ---- phase 3: scatter 4B (src | dl<<17) into reserved dense runs ----
__global__ __launch_bounds__(256) void
k_partA2(const int* __restrict__ src, const int* __restrict__ dst,
         const int* __restrict__ histAll, const int* __restrict__ bbase,
         uint* __restrict__ tmp) {
    __shared__ int gb[NB];
    __shared__ int lcur[NB];
    int tid = threadIdx.x;
    for (int b = tid; b < NB; b += 256) {
        gb[b] = bbase[b] + histAll[blockIdx.x * NB + b];
        lcur[b] = 0;
    }
    __syncthreads();
    int s0 = blockIdx.x * PCHUNK;
    for (int i = s0 + tid; i < s0 + PCHUNK; i += 256) {
        int d = dst[i];
        int b = d >> 8;
        int r = atomicAdd(&lcur[b], 1);
        tmp[gb[b] + r] = (uint)src[i] | ((uint)(d & 255) << 17);
    }
}

// ---- phase 4: per-bucket degree histogram -> dinv + rowptr ----
__global__ __launch_bounds__(256) void
k_partB1(const uint* __restrict__ tmp, const int* __restrict__ bbase,
         float* __restrict__ dinv, int* __restrict__ rowptr) {
    __shared__ int hist[256];
    __shared__ int lds[256];
    int b = blockIdx.x, tid = threadIdx.x;
    int nb0 = b * BW;
    int nodes = (NN - nb0 < BW) ? (NN - nb0) : BW;
    int base = bbase[b];
    int m = bbase[b + 1] - base;
    hist[tid] = 0;
    __syncthreads();
    for (int i = tid; i < m; i += 256)
        atomicAdd(&hist[(tmp[base + i] >> 17) & 255], 1);
    __syncthreads();
    int v = hist[tid];
    lds[tid] = v;
    __syncthreads();
    for (int off = 1; off < 256; off <<= 1) {
        int t = (tid >= off) ? lds[tid - off] : 0;
        __syncthreads();
        lds[tid] += t;
        __syncthreads();
    }
    if (tid < nodes) {
        dinv[nb0 + tid] = rsqrtf(fmaxf((float)v, 1.0f));
        rowptr[nb0 + tid] = base + lds[tid] - v;
    }
    if (b == 0 && tid == 0) rowptr[NN] = NE;
}

// ---- phase 5: per-bucket sort-by-dst -> 4B rec = src | (f16(w)>>1)<<17 ----
__global__ __launch_bounds__(256) void
k_partB2(const uint* __restrict__ tmp, const int* __restrict__ bbase,
         const float* __restrict__ dinv, uint* __restrict__ rec) {
    __shared__ int hist[256];
    __shared__ int lds[256];
    __shared__ int lcur[256];
    int b = blockIdx.x, tid = threadIdx.x;
    int nb0 = b * BW;
    int base = bbase[b];
    int m = bbase[b + 1] - base;
    hist[tid] = 0;
    __syncthreads();
    for (int i = tid; i < m; i += 256)
        atomicAdd(&hist[(tmp[base + i] >> 17) & 255], 1);
    __syncthreads();
    int v = hist[tid];
    lds[tid] = v;
    __syncthreads();
    for (int off = 1; off < 256; off <<= 1) {
        int t = (tid >= off) ? lds[tid - off] : 0;
        __syncthreads();
        lds[tid] += t;
        __syncthreads();
    }
    lcur[tid] = lds[tid] - v;     // exclusive offset within bucket
    __syncthreads();
    for (int i = tid; i < m; i += 256) {
        uint r = tmp[base + i];
        int dl = (r >> 17) & 255;
        int sv = (int)(r & 0x1FFFFu);
        float w = dinv[sv] * dinv[nb0 + dl];
        ushort hw = __half_as_ushort(__float2half_rn(w));
        int p = atomicAdd(&lcur[dl], 1);
        rec[base + p] = (uint)sv | ((uint)(hw >> 1) << 17);
    }
}

// ---- pack x (f32 [node][64]) -> xq (bf16 [node][64], 128B rows) ----
__global__ __launch_bounds__(256) void
k_xq(const float* __restrict__ x, uint2* __restrict__ xq) {
    int t = blockIdx.x * 256 + threadIdx.x;      // [0, NN*16)
    if (t >= NN * 16) return;
    float4 v = ((const float4*)x)[t];
    xq[t] = make_uint2(pack_bf16x2(v.x, v.y), pack_bf16x2(v.z, v.w));
}

// ---- propagation (round-16 optimum): one wave per node; q=lane>>4 owns
//      edge slot, cl=lane&15 owns 4 channels (uint2 bf16).
//      Batch 16 always + 8 predicated (uniform branch) + rare loop. ----
__global__ __launch_bounds__(256) void
k_prop(const int* __restrict__ rowptr, const uint* __restrict__ rec,
       const uint2* __restrict__ h, uint2* __restrict__ hn) {
    int wid  = (int)((blockIdx.x * (long long)blockDim.x + threadIdx.x) >> 6);
    int lane = threadIdx.x & 63;
    if (wid >= NN) return;
    int q  = lane >> 4;
    int cl = lane & 15;
    int start = rowptr[wid];
    int end   = rowptr[wid + 1];
    int safe  = start < NE ? start : NE - 1;

    float a0 = 0.f, a1 = 0.f, a2 = 0.f, a3 = 0.f;

    #define GATHER_FMA(RV, ACTIVE)                                               \
        {                                                                        \
            int   s_ = (int)((RV) & 0x1FFFFu);                                   \
            float wt = (ACTIVE)                                                  \
                ? __half2float(__ushort_as_half((ushort)(((RV) >> 17) << 1)))    \
                : 0.0f;                                                          \
            uint2 hv = h[(long long)s_ * 16 + cl];                               \
            a0 = fmaf(__uint_as_float(hv.x << 16),        wt, a0);               \
            a1 = fmaf(__uint_as_float(hv.x & 0xFFFF0000u), wt, a1);              \
            a2 = fmaf(__uint_as_float(hv.y << 16),        wt, a2);               \
            a3 = fmaf(__uint_as_float(hv.y & 0xFFFF0000u), wt, a3);              \
        }

    {
        uint rv[4];
        #pragma unroll
        for (int j = 0; j < 4; ++j) {
            int ix = start + 4 * j + q;
            rv[j] = rec[ix < end ? ix : safe];
        }
        #pragma unroll
        for (int j = 0; j < 4; ++j) {
            int ix = start + 4 * j + q;
            GATHER_FMA(rv[j], ix < end);
        }
    }
    if (end > start + 16) {
        uint rv[2];
        #pragma unroll
        for (int j = 0; j < 2; ++j) {
            int ix = start + 16 + 4 * j + q;
            rv[j] = rec[ix < end ? ix : safe];
        }
        #pragma unroll
        for (int j = 0; j < 2; ++j) {
            int ix = start + 16 + 4 * j + q;
            GATHER_FMA(rv[j], ix < end);
        }
    }
    for (int p = start + 24; p < end; p += 4) {
        int ix = p + q;
        if (ix < end) {
            uint rv = rec[ix];
            GATHER_FMA(rv, true);
        }
    }
    #undef GATHER_FMA

    a0 += __shfl_xor(a0, 16); a1 += __shfl_xor(a1, 16);
    a2 += __shfl_xor(a2, 16); a3 += __shfl_xor(a3, 16);
    a0 += __shfl_xor(a0, 32); a1 += __shfl_xor(a1, 32);
    a2 += __shfl_xor(a2, 32); a3 += __shfl_xor(a3, 32);

    if (q == 0) {
        long long o = (long long)wid * 16 + cl;
        hn[o] = make_uint2(pack_bf16x2(a0, a1), pack_bf16x2(a2, a3));
    }
}

// ---- deferred combine: out = alpha*x + (1-alpha)/STEPS * sum_t h_t ----
__global__ void k_sum10(const uint2* __restrict__ hbase, const float* __restrict__ x,
                        float* __restrict__ out, int total) {
    int i = blockIdx.x * blockDim.x + threadIdx.x;
    if (i >= total) return;
    float s0 = 0.f, s1 = 0.f, s2 = 0.f, s3 = 0.f;
    #pragma unroll
    for (int t = 0; t < STEPS; ++t) {
        uint2 v = hbase[(size_t)t * (NN * 16) + i];
        s0 += __uint_as_float(v.x << 16);
        s1 += __uint_as_float(v.x & 0xFFFF0000u);
        s2 += __uint_as_float(v.y << 16);
        s3 += __uint_as_float(v.y & 0xFFFF0000u);
    }
    float4 xv = ((const float4*)x)[i];
    float4 r;
    r.x = ALPHA * xv.x + (1.0f - ALPHA) * (s0 * (1.0f / STEPS));
    r.y = ALPHA * xv.y + (1.0f - ALPHA) * (s1 * (1.0f / STEPS));
    r.z = ALPHA * xv.z + (1.0f - ALPHA) * (s2 * (1.0f / STEPS));
    r.w = ALPHA * xv.w + (1.0f - ALPHA) * (s3 * (1.0f / STEPS));
    ((float4*)out)[i] = r;
}

extern "C" void kernel_launch(void* const* d_in, const int* in_sizes, int n_in,
                              void* d_out, int out_size, void* d_ws, size_t ws_size,
                              hipStream_t stream) {
    const float* x  = (const float*)d_in[0];
    const int*   ei = (const int*)d_in[1];     // [2, NE]: row0=src, row1=dst
    const int*   src = ei;
    const int*   dst = ei + NE;
    float* out = (float*)d_out;

    char* ws = (char*)d_ws;
    const size_t MB = 1024 * 1024;
    const size_t KB = 1024;
    int*   histAll = (int*)  (ws);                     // ~400 KB
    float* dinv    = (float*)(ws + 1 * MB);            // 400 KB
    int*   rowptr  = (int*)  (ws + 2 * MB);            // 400 KB (+1)
    int*   bcnt    = (int*)  (ws + 3 * MB);            // tiny
    int*   bbase   = (int*)  (ws + 3 * MB + 64 * KB);  // tiny (+1)
    uint*  rec     = (uint*) (ws + 5 * MB);            // 6.4 MB (final CSR, 4B recs)
    uint2* hbase   = (uint2*)(ws + 20 * MB);           // 10 x 12.8 MB = 128 MB
    uint*  tmp     = (uint*) (ws + 20 * MB);           // 6.4 MB (dead before prop 0)
    uint2* xq      = (uint2*)d_out;                    // 12.8 MB; dead by k_sum10

    const size_t HBUF = (size_t)NN * 16;               // uint2 per h buffer

    k_hist   <<<PBLK, 256, 0, stream>>>(dst, histAll);
    k_colscan<<<NB, 256, 0, stream>>>(histAll, bcnt);
    k_scanb  <<<1, 512, 0, stream>>>(bcnt, bbase);
    k_partA2 <<<PBLK, 256, 0, stream>>>(src, dst, histAll, bbase, tmp);
    k_partB1 <<<NB, 256, 0, stream>>>(tmp, bbase, dinv, rowptr);
    k_partB2 <<<NB, 256, 0, stream>>>(tmp, bbase, dinv, rec);
    k_xq     <<<(NN * 16 + 255) / 256, 256, 0, stream>>>(x, xq);

    const int propBlocks = (NN * 64 + 255) / 256;      // one wave per node

    const uint2* hcur = xq;
    for (int t = 0; t < STEPS; ++t) {
        uint2* hn = hbase + (size_t)t * HBUF;
        k_prop<<<propBlocks, 256, 0, stream>>>(rowptr, rec, hcur, hn);
        hcur = hn;
    }

    const int total = NN * 16;
    k_sum10<<<(total + 255) / 256, 256, 0, stream>>>(hbase, x, out, total);
}